// Round 5
// baseline (238.217 us; speedup 1.0000x reference)
//
#include <hip/hip_runtime.h>
#include <math.h>

// Problem constants (from reference setup_inputs)
constexpr int B = 16;
constexpr int S = 4096;
constexpr int F = 512;
constexpr int L = 32;      // output s-positions per chunk
constexpr int CH = 4;      // chunks per block -> 128 s-positions per block
constexpr int BLOCK = 256; // threads per block; each thread owns one f (grid.x=2)

// out[b,t,f] = sum_i softmax(w)[i]/k_i * sum_{d=-p_i}^{p_i} x[b, clamp(t+d), f]
//
// Round-5 structure: rolling prefix window + chunk-level prefetch pipeline.
//  - prev[32]: prefix P[T-16 .. T+15] carried across chunks (register shift);
//    logical reads drop to 1.25x input (vs 2.0x for independent chunks).
//  - while computing chunk c, the 32 raw loads for chunk c+1 (xn) are already
//    in flight: issued BEFORE the extend/emit phase, pinned by sched_barrier.
//    Prefetch distance = one full compute phase -> memory busy during VALU.
//  - plain stores (NT removed: fetch is already compulsory ~input size, so
//    LLC protection bought nothing; isolates NT as a possible rate culprit).
// Round-4 lesson: monolithic 64-load burst + full drain + compute left the
// memory pipe idle per-wave; scalar and float2 variants both pinned at
// 3.35 TB/s -> structural limit, not per-instruction.
// Register budget: 96 data floats (xv extends in place) + ~20 overhead -> goal
// <=128 VGPR so all 4 blocks/CU are co-resident (1024-block grid, zero tail).
__global__ __launch_bounds__(BLOCK) void msavg_kernel(
    const float* __restrict__ x, const float* __restrict__ kw,
    float* __restrict__ out) {
  const int f  = blockIdx.x * BLOCK + threadIdx.x;  // 0..511
  const int t0 = blockIdx.y * (CH * L);             // block's S-range start
  const int b  = blockIdx.z;

  // softmax over the 4 scale weights, folded with 1/k (uniform -> scalar regs)
  float w0 = kw[0], w1 = kw[1], w2 = kw[2], w3 = kw[3];
  float m  = fmaxf(fmaxf(w0, w1), fmaxf(w2, w3));
  float e0 = expf(w0 - m), e1 = expf(w1 - m), e2 = expf(w2 - m), e3 = expf(w3 - m);
  float inv = 1.0f / (e0 + e1 + e2 + e3);
  const float c3  = e0 * inv * (1.0f / 3.0f);
  const float c7  = e1 * inv * (1.0f / 7.0f);
  const float c15 = e2 * inv * (1.0f / 15.0f);
  const float c31 = e3 * inv * (1.0f / 31.0f);

  const float* xb = x   + ((size_t)b * S) * F + f;
  float*       ob = out + ((size_t)b * S) * F + f;

  const bool ledge = (blockIdx.y == 0);
  const bool redge = (blockIdx.y == gridDim.y - 1);

  // prev[i] = P[T-16+i] (prefix window); xv = raw x for current extension;
  // xn = prefetched raw x for the NEXT chunk's extension.
  float prev[32], xv[32], xn[32];

  // ---- init burst: prev-window raw (t0-16..t0+15) + chunk-0 xv (t0+16..t0+47)
  if (ledge) {
#pragma unroll
    for (int i = 0; i < 32; ++i) {
      int s = t0 - 16 + i;
      s = s < 0 ? 0 : s;              // replicate-left (right never clamps here)
      prev[i] = xb[(size_t)s * F];
    }
  } else {
    const float* p0 = xb + (size_t)(t0 - 16) * F;
#pragma unroll
    for (int i = 0; i < 32; ++i) prev[i] = p0[(size_t)i * F];
  }
  {
    // t0+16 .. t0+47 <= 4015 for every block: never clamps
    const float* p1 = xb + (size_t)(t0 + 16) * F;
#pragma unroll
    for (int j = 0; j < 32; ++j) xv[j] = p1[(size_t)j * F];
  }
  __builtin_amdgcn_sched_barrier(0);

  // prefix the prev window in place: prev[i] = P[t0-16+i]
  {
    float p = 0.0f;
#pragma unroll
    for (int i = 0; i < 32; ++i) { p += prev[i]; prev[i] = p; }
  }

#pragma unroll
  for (int c = 0; c < CH; ++c) {
    const int T = t0 + c * L;

    // 1. prefetch raw x for chunk c+1 (s = T+48 .. T+79) into xn
    if (c + 1 < CH) {
      const int sn = T + 48;
      if (redge && sn + 31 > S - 1) {
#pragma unroll
        for (int j = 0; j < 32; ++j) {
          int s = sn + j;
          s = s > S - 1 ? S - 1 : s;  // replicate-right
          xn[j] = xb[(size_t)s * F];
        }
      } else {
        const float* pn = xb + (size_t)sn * F;
#pragma unroll
        for (int j = 0; j < 32; ++j) xn[j] = pn[(size_t)j * F];
      }
      // pin the prefetch burst above this chunk's compute
      __builtin_amdgcn_sched_barrier(0);
    }

    // 2. extend prefix in place: xv[j] becomes cur[j] = P[T+16+j]
    {
      float p = prev[31];
#pragma unroll
      for (int j = 0; j < 32; ++j) { p += xv[j]; xv[j] = p; }
    }

    // 3. emit 32 outputs t = T + j; prev covers P[T-16..T+15], xv P[T+16..T+47]
#pragma unroll
    for (int j = 0; j < L; ++j) {
      float Pp15 = (j < 1)  ? prev[j + 31] : xv[j - 1];
      float Pp7  = (j < 9)  ? prev[j + 23] : xv[j - 9];
      float Pp3  = (j < 13) ? prev[j + 19] : xv[j - 13];
      float Pp1  = (j < 15) ? prev[j + 17] : xv[j - 15];
      float Pm2  = (j < 18) ? prev[j + 14] : xv[j - 18];
      float Pm4  = (j < 20) ? prev[j + 12] : xv[j - 20];
      float Pm8  = (j < 24) ? prev[j + 8]  : xv[j - 24];
      float Pm16 = prev[j];
      float o = c3  * (Pp1  - Pm2) +
                c7  * (Pp3  - Pm4) +
                c15 * (Pp7  - Pm8) +
                c31 * (Pp15 - Pm16);
      ob[(size_t)(T + j) * F] = o;
    }

    // 4. shift the window: prev <- cur(xv), xv <- xn (SSA renames when unrolled)
    if (c + 1 < CH) {
#pragma unroll
      for (int j = 0; j < 32; ++j) { prev[j] = xv[j]; xv[j] = xn[j]; }
    }
  }
}

extern "C" void kernel_launch(void* const* d_in, const int* in_sizes, int n_in,
                              void* d_out, int out_size, void* d_ws, size_t ws_size,
                              hipStream_t stream) {
  const float* x  = (const float*)d_in[0];  // [16, 4096, 512] fp32
  const float* kw = (const float*)d_in[1];  // [4] fp32
  float* out = (float*)d_out;               // [16, 4096, 512] fp32
  (void)in_sizes; (void)n_in; (void)out_size; (void)d_ws; (void)ws_size;

  dim3 grid(F / BLOCK, S / (CH * L), B);  // (2, 32, 16) = 1024 blocks, 4/CU
  msavg_kernel<<<grid, BLOCK, 0, stream>>>(x, kw, out);
}